// Round 5
// baseline (3594.291 us; speedup 1.0000x reference)
//
#include <hip/hip_runtime.h>
#include <cstdint>

// ---------------------------------------------------------------------------
// Autoformer forward — hybrid precision v10 (R15):
//   * R15a: FFN1 moved to gemm_hf — A staged as f32 via global_load_lds
//     (BK=32, 3-bit XOR seg swizzle), f32->fp16 cvt on fragment read.
//     R14's reg-staged A exposed full load latency at every barrier.
//   * R15b: XCD-aware bijective block swizzle in gemm_h/gemm_hf/gemm_z
//     (A-panels fetched once per device instead of once per XCD).
//   * R14a: conv_embed register-caches xs columns.
//   * R13: proj1 read-once split-K; colmean partials; per-chunk FFN dataflow.
//   * R11: gt_k replaced by tsplit2_k + split-fp16 MFMA gemm_z @ 512^3.
// Inputs f32 (runtime-detected from x_mark_enc; bf16 fallback kept).
//
// Workspace (bytes), total ~148.1 MB:
//   X    @ 0          : f32 residual 64Mi; FFN: Hb fp16 hidden (0..32Mi)
//   XH   @ 67108864   : fp16 X-high 32Mi | FFN: S2 f32 64Mi (spans XH+XL!)
//   XL   @ 100663296  : fp16 X-low*512 32Mi / AGh   (S2 second half!)
//   ZH   @ 134217728  : fp16 Z-high chunk 4Mi \ Ph 8Mi (V chunk)
//   ZL   @ 138412032  : fp16 Z-low chunk 4Mi  /  | final: CMp
//   SH   @ 142606336  : Phase A: wT | KTH/KTL/QTH/QTL + GH/GL
//                       Phase B: Wvh/Woh/W1h/W2h
//   MV   @ 147849216, WGT @ 147980288, DLY @ 147981312, FLAG @ 148068352
//   PB2  @ 67108864 (over S2, dead at proj time)
// ---------------------------------------------------------------------------

using u16 = unsigned short;
typedef _Float16 f16x8 __attribute__((ext_vector_type(8)));
typedef float f32x4 __attribute__((ext_vector_type(4)));

#define BB 32
#define LL 1024
#define DD 512
#define DFF 2048

__device__ __forceinline__ float bf2f(u16 u) {
  union { uint32_t i; float f; } v; v.i = ((uint32_t)u) << 16; return v.f;
}
__device__ __forceinline__ u16 f2bf(float f) {
  union { float f; uint32_t i; } v; v.f = f;
  uint32_t r = (v.i + 0x7FFFu + ((v.i >> 16) & 1u)) >> 16;
  return (u16)r;
}
__device__ __forceinline__ float ldi(const void* p, long i, int isf) {
  return isf ? ((const float*)p)[i] : bf2f(((const u16*)p)[i]);
}
__device__ __forceinline__ float gelu_f(float x) {
  return 0.5f * x * (1.0f + erff(x * 0.70710678118654752440f));
}
// async 16B global -> LDS (wave-uniform LDS base + lane*16)
__device__ __forceinline__ void gld16(const void* g, void* l) {
  __builtin_amdgcn_global_load_lds(
      (const __attribute__((address_space(1))) void*)g,
      (__attribute__((address_space(3))) void*)l, 16, 0, 0);
}
// XCD-aware bijective block swizzle (requires nwg % 8 == 0, all grids comply)
__device__ __forceinline__ void swz8(int& bx, int& by) {
  int gx = gridDim.x;
  int nwg = gx * gridDim.y;
  int bid = by * gx + bx;
  int q = nwg >> 3;
  int s = (bid & 7) * q + (bid >> 3);
  bx = s % gx;
  by = s / gx;
}

union H8 { f16x8 v; uint4 u; _Float16 h[8]; };
union H4 { uint2 u; _Float16 h[4]; };

__global__ void detect_k(const uint32_t* __restrict__ mark, int* __restrict__ FLAG) {
  if (threadIdx.x == 0) FLAG[0] = (mark[0] == 0x3F800000u) ? 1 : 0;
}

// transpose conv weight to wT[(c*3+t)*512 + d], f32. grid 126, block 256
__global__ __launch_bounds__(256) void wT_k(const void* __restrict__ w,
                                            float* __restrict__ wT,
                                            const int* __restrict__ FLAG) {
  const int isf = *FLAG;
  int idx = blockIdx.x * 256 + threadIdx.x;
  if (idx >= 63 * DD) return;
  int c3t = idx / DD;
  int d = idx - c3t * DD;
  wT[idx] = ldi(w, (long)d * 63 + c3t, isf);
}

// ---------------------------------------------------------------------------
// Conv1d circular embedding + fused split. grid (L/16, B), block 256.
// ---------------------------------------------------------------------------
__global__ __launch_bounds__(256) void conv_embed_k(
    const void* __restrict__ xe, const float* __restrict__ wT,
    float* __restrict__ X, _Float16* __restrict__ XH, _Float16* __restrict__ XL,
    const int* __restrict__ FLAG) {
  const int isf = *FLAG;
  int b = blockIdx.y;
  int l0 = blockIdx.x * 16;
  __shared__ float xs[18][21];
  int tid = threadIdx.x;
  for (int i = tid; i < 18 * 21; i += 256) {
    int r = i / 21, c = i % 21;
    int row = (l0 - 1 + r + LL) & (LL - 1);
    xs[r][c] = ldi(xe, ((long)b * LL + row) * 21 + c, isf);
  }
  __syncthreads();
  float acc0[16], acc1[16];
#pragma unroll
  for (int ll = 0; ll < 16; ll++) { acc0[ll] = 0.0f; acc1[ll] = 0.0f; }
  for (int c = 0; c < 21; c++) {
    float xreg[18];
#pragma unroll
    for (int r = 0; r < 18; r++) xreg[r] = xs[r][c];
#pragma unroll
    for (int t = 0; t < 3; t++) {
      float w0 = wT[(c * 3 + t) * DD + tid];
      float w1 = wT[(c * 3 + t) * DD + tid + 256];
#pragma unroll
      for (int ll = 0; ll < 16; ll++) {
        acc0[ll] = fmaf(w0, xreg[t + ll], acc0[ll]);
        acc1[ll] = fmaf(w1, xreg[t + ll], acc1[ll]);
      }
    }
  }
#pragma unroll
  for (int ll = 0; ll < 16; ll++) {
    long base = ((long)b * LL + l0 + ll) * DD;
    float v0 = acc0[ll], v1 = acc1[ll];
    X[base + tid] = v0;
    X[base + tid + 256] = v1;
    _Float16 h0 = (_Float16)v0, h1 = (_Float16)v1;
    XH[base + tid] = h0;
    XH[base + tid + 256] = h1;
    XL[base + tid] = (_Float16)((v0 - (float)h0) * 512.0f);
    XL[base + tid + 256] = (_Float16)((v1 - (float)h1) * 512.0f);
  }
}

// ---------------------------------------------------------------------------
// transpose + split BOTH Wq/Wk in one launch. grid (8, 8, 2), block 256.
// ---------------------------------------------------------------------------
__global__ __launch_bounds__(256) void tsplit2_k(
    const void* __restrict__ W1, const void* __restrict__ W2, long off,
    _Float16* __restrict__ T1H, _Float16* __restrict__ T1L,
    _Float16* __restrict__ T2H, _Float16* __restrict__ T2L,
    const int* __restrict__ FLAG) {
  const int isf = *FLAG;
  const void* W = blockIdx.z ? W2 : W1;
  _Float16* TH = blockIdx.z ? T2H : T1H;
  _Float16* TL = blockIdx.z ? T2L : T1L;
  __shared__ float t[64][65];
  const int f0 = blockIdx.x * 64, m0 = blockIdx.y * 64;
  const int tid = threadIdx.x;
  const int c = tid & 63, rb = tid >> 6;
#pragma unroll
  for (int r = rb; r < 64; r += 4)
    t[r][c] = ldi(W, off + (long)(f0 + r) * DD + m0 + c, isf);
  __syncthreads();
#pragma unroll
  for (int r = rb; r < 64; r += 4) {
    float v = t[c][r];
    long o = (long)(m0 + r) * DD + f0 + c;
    _Float16 hv = (_Float16)v;
    TH[o] = hv;
    TL[o] = (_Float16)((v - (float)hv) * 512.0f);
  }
}

// split f32 -> (fp16 high, fp16 low*512). 8 elems/thread.
__global__ __launch_bounds__(256) void split_k(const float* __restrict__ src,
                                               _Float16* __restrict__ dh,
                                               _Float16* __restrict__ dl, int n) {
  long i = ((long)blockIdx.x * 256 + threadIdx.x) * 8;
  if (i >= n) return;
  float4 a = *(const float4*)(src + i);
  float4 b = *(const float4*)(src + i + 4);
  float x[8] = {a.x, a.y, a.z, a.w, b.x, b.y, b.z, b.w};
  H8 h, l;
#pragma unroll
  for (int j = 0; j < 8; j++) {
    _Float16 hv = (_Float16)x[j];
    h.h[j] = hv;
    l.h[j] = (_Float16)((x[j] - (float)hv) * 512.0f);
  }
  *(uint4*)(dh + i) = h.u;
  *(uint4*)(dl + i) = l.u;
}

// all four Phase-B weights -> fp16 in one launch. grid 1280, block 256
__global__ __launch_bounds__(256) void wcvt6_k(
    const void* __restrict__ Wv, const void* __restrict__ Wo,
    const void* __restrict__ W1, const void* __restrict__ W2,
    long oW, long oF,
    _Float16* __restrict__ Wvh, _Float16* __restrict__ Woh,
    _Float16* __restrict__ W1h, _Float16* __restrict__ W2h,
    const int* __restrict__ FLAG) {
  const int isf = *FLAG;
  long e = ((long)blockIdx.x * 256 + threadIdx.x) * 8;
  const void* src; long soff; _Float16* dst;
  if (e < 262144) { src = Wv; soff = oW + e; dst = Wvh + e; }
  else if (e < 524288) { src = Wo; soff = oW + (e - 262144); dst = Woh + (e - 262144); }
  else if (e < 1572864) { src = W1; soff = oF + (e - 524288); dst = W1h + (e - 524288); }
  else { src = W2; soff = oF + (e - 1572864); dst = W2h + (e - 1572864); }
  H8 r;
  if (isf) {
    const float* s = (const float*)src + soff;
    float4 a = *(const float4*)s;
    float4 b = *(const float4*)(s + 4);
    r.h[0] = (_Float16)a.x; r.h[1] = (_Float16)a.y;
    r.h[2] = (_Float16)a.z; r.h[3] = (_Float16)a.w;
    r.h[4] = (_Float16)b.x; r.h[5] = (_Float16)b.y;
    r.h[6] = (_Float16)b.z; r.h[7] = (_Float16)b.w;
  } else {
    const u16* s = (const u16*)src + soff;
    uint4 u = *(const uint4*)s;
    r.h[0] = (_Float16)bf2f((u16)(u.x & 0xffff));
    r.h[1] = (_Float16)bf2f((u16)(u.x >> 16));
    r.h[2] = (_Float16)bf2f((u16)(u.y & 0xffff));
    r.h[3] = (_Float16)bf2f((u16)(u.y >> 16));
    r.h[4] = (_Float16)bf2f((u16)(u.z & 0xffff));
    r.h[5] = (_Float16)bf2f((u16)(u.z >> 16));
    r.h[6] = (_Float16)bf2f((u16)(u.w & 0xffff));
    r.h[7] = (_Float16)bf2f((u16)(u.w >> 16));
  }
  *(uint4*)(dst) = r.u;
}

// ---------------------------------------------------------------------------
// split-fp16 MFMA GEMM: Z = A @ W^T (split in/out). BK=32. (R9-verified)
// ---------------------------------------------------------------------------
__global__ __launch_bounds__(256) void gemm_z(
    const _Float16* __restrict__ Ah, const _Float16* __restrict__ Al,
    const _Float16* __restrict__ Bh, const _Float16* __restrict__ Bl,
    _Float16* __restrict__ Zh, _Float16* __restrict__ Zl,
    int M, int N, int K) {
  __shared__ __align__(16) _Float16 AsH[128 * 32];
  __shared__ __align__(16) _Float16 AsL[128 * 32];
  __shared__ __align__(16) _Float16 BsH[128 * 32];
  __shared__ __align__(16) _Float16 BsL[128 * 32];
  int bx = blockIdx.x, by = blockIdx.y;
  swz8(bx, by);
  const int n0 = bx * 128, m0 = by * 128;
  const int tid = threadIdx.x;
  const int lane = tid & 63, wvi = tid >> 6;
  const int wm = (wvi >> 1) * 64, wn = (wvi & 1) * 64;
  const int l15 = lane & 15, quad = lane >> 4;
  const int ib = wvi * 128 + lane;
  const int r0 = ib >> 2, r1 = r0 + 16;
  const int c0 = ((ib & 3) ^ ((r0 >> 1) & 3)) * 8;
  const int c1 = ((ib & 3) ^ ((r1 >> 1) & 3)) * 8;
  const int lb0 = wvi * 1024, lb1 = wvi * 1024 + 512;
  const long ga0 = (long)(m0 + r0) * K + c0;
  const long ga1 = (long)(m0 + r1) * K + c1;
  const long gb0 = (long)(n0 + r0) * K + c0;
  const long gb1 = (long)(n0 + r1) * K + c1;
  f32x4 aM[4][4], aC[4][4];
#pragma unroll
  for (int i = 0; i < 4; i++)
#pragma unroll
    for (int j = 0; j < 4; j++) {
      aM[i][j] = (f32x4){0.f, 0.f, 0.f, 0.f};
      aC[i][j] = (f32x4){0.f, 0.f, 0.f, 0.f};
    }
  for (int k0 = 0; k0 < K; k0 += 32) {
    __syncthreads();
    gld16(Ah + ga0 + k0, AsH + lb0);
    gld16(Ah + ga1 + k0, AsH + lb1);
    gld16(Al + ga0 + k0, AsL + lb0);
    gld16(Al + ga1 + k0, AsL + lb1);
    gld16(Bh + gb0 + k0, BsH + lb0);
    gld16(Bh + gb1 + k0, BsH + lb1);
    gld16(Bl + gb0 + k0, BsL + lb0);
    gld16(Bl + gb1 + k0, BsL + lb1);
    __syncthreads();
    f16x8 fah[4], fal[4], fbh[4], fbl[4];
#pragma unroll
    for (int mi = 0; mi < 4; mi++) {
      int r = wm + mi * 16 + l15;
      int o = r * 32 + ((quad ^ ((r >> 1) & 3)) * 8);
      fah[mi] = *(const f16x8*)&AsH[o];
      fal[mi] = *(const f16x8*)&AsL[o];
    }
#pragma unroll
    for (int ni = 0; ni < 4; ni++) {
      int r = wn + ni * 16 + l15;
      int o = r * 32 + ((quad ^ ((r >> 1) & 3)) * 8);
      fbh[ni] = *(const f16x8*)&BsH[o];
      fbl[ni] = *(const f16x8*)&BsL[o];
    }
#pragma unroll
    for (int mi = 0; mi < 4; mi++)
#pragma unroll
      for (int ni = 0; ni < 4; ni++) {
        aM[mi][ni] = __builtin_amdgcn_mfma_f32_16x16x32_f16(
            fah[mi], fbh[ni], aM[mi][ni], 0, 0, 0);
        aC[mi][ni] = __builtin_amdgcn_mfma_f32_16x16x32_f16(
            fah[mi], fbl[ni], aC[mi][ni], 0, 0, 0);
        aC[mi][ni] = __builtin_amdgcn_mfma_f32_16x16x32_f16(
            fal[mi], fbh[ni], aC[mi][ni], 0, 0, 0);
      }
  }
#pragma unroll
  for (int mi = 0; mi < 4; mi++) {
    int rowg = m0 + wm + mi * 16 + quad * 4;
#pragma unroll
    for (int ni = 0; ni < 4; ni++) {
      int colg = n0 + wn + ni * 16 + l15;
#pragma unroll
      for (int rr = 0; rr < 4; rr++) {
        long off = (long)(rowg + rr) * N + colg;
        float z = aM[mi][ni][rr] + aC[mi][ni][rr] * (1.0f / 512.0f);
        _Float16 zh = (_Float16)z;
        Zh[off] = zh;
        Zl[off] = (_Float16)((z - (float)zh) * 512.0f);
      }
    }
  }
}

// ---------------------------------------------------------------------------
// split-fp16 MFMA Z.X^T + fused wrapped-diagonal mean reduce. BK=32.
// ---------------------------------------------------------------------------
__global__ __launch_bounds__(256) void qkmv_hl(
    const _Float16* __restrict__ Zh, const _Float16* __restrict__ Zl,
    const _Float16* __restrict__ Xh, const _Float16* __restrict__ Xl,
    float* __restrict__ MV) {
  __shared__ __align__(16) _Float16 AsH[128 * 32];
  __shared__ __align__(16) _Float16 AsL[128 * 32];
  __shared__ __align__(16) _Float16 BsH[128 * 32];
  __shared__ __align__(16) _Float16 BsL[128 * 32];
  __shared__ float diag[255];
  const int bz = blockIdx.z;
  const long bb = (long)bz * LL * DD;
  const int n0 = blockIdx.x * 128, m0 = blockIdx.y * 128;
  const int tid = threadIdx.x;
  const int lane = tid & 63, wvi = tid >> 6;
  const int wm = (wvi >> 1) * 64, wn = (wvi & 1) * 64;
  const int l15 = lane & 15, quad = lane >> 4;
  const int ib = wvi * 128 + lane;
  const int r0 = ib >> 2, r1 = r0 + 16;
  const int c0 = ((ib & 3) ^ ((r0 >> 1) & 3)) * 8;
  const int c1 = ((ib & 3) ^ ((r1 >> 1) & 3)) * 8;
  const int lb0 = wvi * 1024, lb1 = wvi * 1024 + 512;
  const long ga0 = bb + (long)(m0 + r0) * DD + c0;
  const long ga1 = bb + (long)(m0 + r1) * DD + c1;
  const long gb0 = bb + (long)(n0 + r0) * DD + c0;
  const long gb1 = bb + (long)(n0 + r1) * DD + c1;
  if (tid < 255) diag[tid] = 0.0f;
  f32x4 aM[4][4], aC[4][4];
#pragma unroll
  for (int i = 0; i < 4; i++)
#pragma unroll
    for (int j = 0; j < 4; j++) {
      aM[i][j] = (f32x4){0.f, 0.f, 0.f, 0.f};
      aC[i][j] = (f32x4){0.f, 0.f, 0.f, 0.f};
    }
  for (int k0 = 0; k0 < DD; k0 += 32) {
    __syncthreads();
    gld16(Zh + ga0 + k0, AsH + lb0);
    gld16(Zh + ga1 + k0, AsH + lb1);
    gld16(Zl + ga0 + k0, AsL + lb0);
    gld16(Zl + ga1 + k0, AsL + lb1);
    gld16(Xh + gb0 + k0, BsH + lb0);
    gld16(Xh + gb1 + k0, BsH + lb1);
    gld16(Xl + gb0 + k0, BsL + lb0);
    gld16(Xl + gb1 + k0, BsL + lb1);
    __syncthreads();
    f16x8 fah[4], fal[4], fbh[4], fbl[4];
#pragma unroll
    for (int mi = 0; mi < 4; mi++) {
      int r = wm + mi * 16 + l15;
      int o = r * 32 + ((quad ^ ((r >> 1) & 3)) * 8);
      fah[mi] = *(const f16x8*)&AsH[o];
      fal[mi] = *(const f16x8*)&AsL[o];
    }
#pragma unroll
    for (int ni = 0; ni < 4; ni++) {
      int r = wn + ni * 16 + l15;
      int o = r * 32 + ((quad ^ ((r >> 1) & 3)) * 8);
      fbh[ni] = *(const f16x8*)&BsH[o];
      fbl[ni] = *(const f16x8*)&BsL[o];
    }
#pragma unroll
    for (int mi = 0; mi < 4; mi++)
#pragma unroll
      for (int ni = 0; ni < 4; ni++) {
        aM[mi][ni] = __builtin_amdgcn_mfma_f32_16x16x32_f16(
            fah[mi], fbh[ni], aM[mi][ni], 0, 0, 0);
        aC[mi][ni] = __builtin_amdgcn_mfma_f32_16x16x32_f16(
            fah[mi], fbl[ni], aC[mi][ni], 0, 0, 0);
        aC[mi][ni] = __builtin_amdgcn_mfma_f32_16x16x32_f16(
            fal[mi], fbh[ni], aC[mi][ni], 0, 0, 0);
      }
  }
#pragma unroll
  for (int g = -3; g <= 3; g++) {
#pragma unroll
    for (int rr = 0; rr < 4; rr++) {
      float s = 0.0f;
#pragma unroll
      for (int mi = 0; mi < 4; mi++) {
        int ni = mi - g;
        if (ni >= 0 && ni < 4)
          s += aM[mi][ni][rr] + aC[mi][ni][rr] * (1.0f / 512.0f);
      }
      int d = 127 + (wm - wn) + g * 16 + quad * 4 + rr - l15;
      atomicAdd(&diag[d], s);
    }
  }
  __syncthreads();
  if (tid < 255) {
    int tau = (m0 - n0 + tid - 127 + LL) & (LL - 1);
    atomicAdd(&MV[(long)bz * LL + tau], diag[tid] * (1.0f / 512.0f));
  }
}

// ---------------------------------------------------------------------------
// fp16 MFMA GEMM, BK=64: C[M,N] = act( A[M,K] @ W[N,K]^T + bias + R )
// FLAGS: 1=bias 2=gelu 4=residual 8=out-fp16
// ---------------------------------------------------------------------------
template <int FLAGS>
__global__ __launch_bounds__(256) void gemm_h(
    const _Float16* __restrict__ A, const _Float16* __restrict__ W,
    const void* __restrict__ biasBase, long bOff,
    const float* __restrict__ R, void* __restrict__ Cout,
    int M, int N, int K, const int* __restrict__ FLAG) {
  constexpr bool HAS_BIAS = (FLAGS & 1) != 0;
  constexpr bool DO_GELU = (FLAGS & 2) != 0;
  constexpr bool DO_RES = (FLAGS & 4) != 0;
  constexpr bool OUT_H = (FLAGS & 8) != 0;
  __shared__ __align__(16) _Float16 As[128 * 64];
  __shared__ __align__(16) _Float16 Bs[128 * 64];
  int bx = blockIdx.x, by = blockIdx.y;
  swz8(bx, by);
  const int n0 = bx * 128, m0 = by * 128;
  const int tid = threadIdx.x;
  const int lane = tid & 63, wvi = tid >> 6;
  const int wm = (wvi >> 1) * 64, wn = (wvi & 1) * 64;
  const int l15 = lane & 15, quad = lane >> 4;
  const _Float16* gA[4];
  const _Float16* gB[4];
  int ldsOff[4];
#pragma unroll
  for (int j = 0; j < 4; j++) {
    int ib = wvi * 256 + j * 64 + lane;
    int row = ib >> 3, p = ib & 7;
    int gc = ((p & 4) | ((p & 3) ^ ((row >> 1) & 3))) * 8;
    gA[j] = A + (long)(m0 + row) * K + gc;
    gB[j] = W + (long)(n0 + row) * K + gc;
    ldsOff[j] = wvi * 2048 + j * 512;
  }
  f32x4 acc[4][4];
#pragma unroll
  for (int i = 0; i < 4; i++)
#pragma unroll
    for (int j = 0; j < 4; j++) acc[i][j] = (f32x4){0.f, 0.f, 0.f, 0.f};
  for (int k0 = 0; k0 < K; k0 += 64) {
    __syncthreads();
#pragma unroll
    for (int j = 0; j < 4; j++) gld16(gA[j] + k0, As + ldsOff[j]);
#pragma unroll
    for (int j = 0; j < 4; j++) gld16(gB[j] + k0, Bs + ldsOff[j]);
    __syncthreads();
#pragma unroll
    for (int ks = 0; ks < 2; ks++) {
      f16x8 af[4], bfr[4];
#pragma unroll
      for (int mi = 0; mi < 4; mi++) {
        int r = wm + mi * 16 + l15;
        af[mi] = *(const f16x8*)&As[r * 64 + (ks * 4 + (quad ^ ((r >> 1) & 3))) * 8];
      }
#pragma unroll
      for (int ni = 0; ni < 4; ni++) {
        int r = wn + ni * 16 + l15;
        bfr[ni] = *(const f16x8*)&Bs[r * 64 + (ks * 4 + (quad ^ ((r >> 1) & 3))) * 8];
      }
#pragma unroll
      for (int mi = 0; mi < 4; mi++)
#pragma unroll
        for (int ni = 0; ni < 4; ni++)
          acc[mi][ni] = __builtin_amdgcn_mfma_f32_16x16x32_f16(
              af[mi], bfr[ni], acc[mi][ni], 0, 0, 0);
    }
  }
  float bcol[4];
  if constexpr (HAS_BIAS) {
    const int isf = *FLAG;
#pragma unroll
    for (int ni = 0; ni < 4; ni++)
      bcol[ni] = ldi(biasBase, bOff + n0 + wn + ni * 16 + l15, isf);
  }
#pragma unroll
  for (int mi = 0; mi < 4; mi++) {
    int rowg = m0 + wm + mi * 16 + quad * 4;
#pragma unroll
    for (int ni = 0; ni < 4; ni++) {
      int colg = n0 + wn + ni * 16 + l15;
#pragma unroll
      for (int rr = 0; rr < 4; rr++) {
        long off = (long)(rowg + rr) * N + colg;
        float v = acc[mi][ni][rr];
        if constexpr (HAS_BIAS) v += bcol[ni];
        if constexpr (DO_RES) v += R[off];
        if constexpr (DO_GELU) v = gelu_f(v);
        if constexpr (OUT_H) ((_Float16*)Cout)[off] = (_Float16)v;
        else ((float*)Cout)[off] = v;
      }
    }
  }
}

// ---------------------------------------------------------------------------
// FFN1 GEMM: C[M,N] = gelu(Af32[M,K] @ W[N,K]^T) -> fp16. BK=32.
// A staged as f32 via global_load_lds (async), cvt->fp16 on fragment read.
// A rows: 32 f32 = 8 segs of 4 f32, XOR-swizzled by (row&7) (bank-spread).
// B rows: 32 fp16, gemm_z staging pattern (verified).
// ---------------------------------------------------------------------------
__global__ __launch_bounds__(256) void gemm_hf(
    const float* __restrict__ A, const _Float16* __restrict__ W,
    _Float16* __restrict__ Cout, int M, int N, int K) {
  __shared__ __align__(16) float As32[128 * 32];   // 16 KB
  __shared__ __align__(16) _Float16 Bs[128 * 32];  // 8 KB
  int bx = blockIdx.x, by = blockIdx.y;
  swz8(bx, by);
  const int n0 = bx * 128, m0 = by * 128;
  const int tid = threadIdx.x;
  const int lane = tid & 63, wvi = tid >> 6;
  const int wm = (wvi >> 1) * 64, wn = (wvi & 1) * 64;
  const int l15 = lane & 15, quad = lane >> 4;
  // A staging pointers: slot ib = j*256+tid -> row ib>>3, seg p = ib&7,
  // global seg gs = p ^ (row&7). LDS dst linear (wave base + lane*16).
  const float* gAf[4];
#pragma unroll
  for (int j = 0; j < 4; j++) {
    int ib = j * 256 + tid;
    int row = ib >> 3, p = ib & 7;
    int gs = p ^ (row & 7);
    gAf[j] = A + (long)(m0 + row) * K + gs * 4;
  }
  // B staging: gemm_z pattern
  const int ibb = wvi * 128 + lane;
  const int r0 = ibb >> 2, r1 = r0 + 16;
  const int c0 = ((ibb & 3) ^ ((r0 >> 1) & 3)) * 8;
  const int c1 = ((ibb & 3) ^ ((r1 >> 1) & 3)) * 8;
  const int lb0 = wvi * 1024, lb1 = wvi * 1024 + 512;
  const long gb0 = (long)(n0 + r0) * K + c0;
  const long gb1 = (long)(n0 + r1) * K + c1;
  f32x4 acc[4][4];
#pragma unroll
  for (int i = 0; i < 4; i++)
#pragma unroll
    for (int j = 0; j < 4; j++) acc[i][j] = (f32x4){0.f, 0.f, 0.f, 0.f};
  for (int k0 = 0; k0 < K; k0 += 32) {
    __syncthreads();
#pragma unroll
    for (int j = 0; j < 4; j++)
      gld16(gAf[j] + k0, As32 + j * 1024 + wvi * 256);
    gld16(W + gb0 + k0, Bs + lb0);
    gld16(W + gb1 + k0, Bs + lb1);
    __syncthreads();
    f16x8 af[4], bf[4];
#pragma unroll
    for (int mi = 0; mi < 4; mi++) {
      int r = wm + mi * 16 + l15;
      int p0 = (2 * quad) ^ (r & 7);
      int p1 = (2 * quad + 1) ^ (r & 7);
      f32x4 v0 = *(const f32x4*)&As32[r * 32 + p0 * 4];
      f32x4 v1 = *(const f32x4*)&As32[r * 32 + p1 * 4];
      H8 h;
      h.h[0] = (_Float16)v0[0]; h.h[1] = (_Float16)v0[1];
      h.h[2] = (_Float16)v0[2]; h.h[3] = (_Float16)v0[3];
      h.h[4] = (_Float16)v1[0]; h.h[5] = (_Float16)v1[1];
      h.h[6] = (_Float16)v1[2]; h.h[7] = (_Float16)v1[3];
      af[mi] = h.v;
    }
#pragma unroll
    for (int ni = 0; ni < 4; ni++) {
      int r = wn + ni * 16 + l15;
      int o = r * 32 + ((quad ^ ((r >> 1) & 3)) * 8);
      bf[ni] = *(const f16x8*)&Bs[o];
    }
#pragma unroll
    for (int mi = 0; mi < 4; mi++)
#pragma unroll
      for (int ni = 0; ni < 4; ni++)
        acc[mi][ni] = __builtin_amdgcn_mfma_f32_16x16x32_f16(
            af[mi], bf[ni], acc[mi][ni], 0, 0, 0);
  }
#pragma unroll
  for (int mi = 0; mi < 4; mi++) {
    int rowg = m0 + wm + mi * 16 + quad * 4;
#pragma unroll
    for (int ni = 0; ni < 4; ni++) {
      int colg = n0 + wn + ni * 16 + l15;
#pragma unroll
      for (int rr = 0; rr < 4; rr++) {
        float v = gelu_f(acc[mi][ni][rr]);
        Cout[(long)(rowg + rr) * N + colg] = (_Float16)v;
      }
    }
  }
}

// ---------------------------------------------------------------------------
// top-6 of MV[b,:] + softmax.  grid (32), block 256
// ---------------------------------------------------------------------------
__global__ __launch_bounds__(256) void topk_k(const float* __restrict__ MV,
                                              float* __restrict__ WGT,
                                              int* __restrict__ DLY) {
  int b = blockIdx.x;
  __shared__ float vals[LL];
  __shared__ float rv[256];
  __shared__ int ri[256];
  __shared__ float selv[6];
  int tid = threadIdx.x;
  for (int i = tid; i < LL; i += 256) vals[i] = MV[(long)b * LL + i];
  __syncthreads();
  for (int it = 0; it < 6; it++) {
    float bv = -1e30f;
    int bi = LL - 1;
    for (int i = tid; i < LL; i += 256) {
      float v = vals[i];
      if (v > bv || (v == bv && i < bi)) { bv = v; bi = i; }
    }
    rv[tid] = bv; ri[tid] = bi;
    __syncthreads();
    for (int st = 128; st > 0; st >>= 1) {
      if (tid < st) {
        float ov = rv[tid + st]; int oi = ri[tid + st];
        if (ov > rv[tid] || (ov == rv[tid] && oi < ri[tid])) {
          rv[tid] = ov; ri[tid] = oi;
        }
      }
      __syncthreads();
    }
    if (tid == 0) {
      selv[it] = rv[0];
      DLY[b * 6 + it] = ri[0];
      vals[ri[0]] = -1e30f;
    }
    __syncthreads();
  }
  if (tid == 0) {
    float mx = selv[0];
    float e[6], s = 0.0f;
    for (int i = 0; i < 6; i++) { e[i] = expf(selv[i] - mx); s += e[i]; }
    for (int i = 0; i < 6; i++) WGT[b * 6 + i] = e[i] / s;
  }
}

// ---------------------------------------------------------------------------
// time-delay aggregation, fp16 in/out (chunk-local): grid (1024, NB), block 128
// ---------------------------------------------------------------------------
__global__ __launch_bounds__(128) void agg_k(const _Float16* __restrict__ V,
                                             const float* __restrict__ WGT,
                                             const int* __restrict__ DLY,
                                             _Float16* __restrict__ O) {
  int l = blockIdx.x, b = blockIdx.y;
  int tid = threadIdx.x;
  float w[6]; int dl[6];
#pragma unroll
  for (int i = 0; i < 6; i++) { w[i] = WGT[b * 6 + i]; dl[i] = DLY[b * 6 + i]; }
  long base = (long)b * LL * DD;
  int d = tid * 4;
  float a0 = 0, a1 = 0, a2 = 0, a3 = 0;
#pragma unroll
  for (int i = 0; i < 6; i++) {
    int row = (l + dl[i]) & (LL - 1);
    H4 t; t.u = *(const uint2*)&V[base + (long)row * DD + d];
    a0 += w[i] * (float)t.h[0];
    a1 += w[i] * (float)t.h[1];
    a2 += w[i] * (float)t.h[2];
    a3 += w[i] * (float)t.h[3];
  }
  H4 r;
  r.h[0] = (_Float16)a0; r.h[1] = (_Float16)a1;
  r.h[2] = (_Float16)a2; r.h[3] = (_Float16)a3;
  *(uint2*)&O[base + (long)l * DD + d] = r.u;
}

// ---------------------------------------------------------------------------
// series_decomp residual (f32 out only, race-free). grid (2, 16, 32), block 256
// ---------------------------------------------------------------------------
__global__ __launch_bounds__(256) void decomp_k(const float* __restrict__ Xin,
                                                float* __restrict__ Out) {
  int d = blockIdx.x * 256 + threadIdx.x;
  int l0 = blockIdx.y * 64;
  int b = blockIdx.z;
  const float* xb = Xin + (long)b * LL * DD + d;
  float* ob = Out + (long)b * LL * DD + d;
  float wsum = 0.0f;
  for (int j = l0 - 12; j <= l0 + 12; j++) {
    int jj = min(max(j, 0), LL - 1);
    wsum += xb[(long)jj * DD];
  }
  for (int l = l0; l < l0 + 64; l++) {
    float xv = xb[(long)l * DD];
    ob[(long)l * DD] = xv - wsum * (1.0f / 25.0f);
    int ja = min(l + 13, LL - 1);
    int jr = max(l - 12, 0);
    wsum += xb[(long)ja * DD] - xb[(long)jr * DD];
  }
}

// special layernorm. grid (1024,32), block 256
__global__ __launch_bounds__(256) void ln_k(const float* __restrict__ X,
                                            const void* __restrict__ g,
                                            const void* __restrict__ be,
                                            float* __restrict__ XHo,
                                            const int* __restrict__ FLAG) {
  const int isf = *FLAG;
  int l = blockIdx.x, b = blockIdx.y;
  const float* xr = X + ((long)b * LL + l) * DD;
  int tid = threadIdx.x;
  float x0 = xr[tid], x1 = xr[tid + 256];
  __shared__ float rs[256], rq[256];
  rs[tid] = x0 + x1;
  rq[tid] = x0 * x0 + x1 * x1;
  __syncthreads();
  for (int st = 128; st > 0; st >>= 1) {
    if (tid < st) { rs[tid] += rs[tid + st]; rq[tid] += rq[tid + st]; }
    __syncthreads();
  }
  float mu = rs[0] * (1.0f / 512.0f);
  float var = rq[0] * (1.0f / 512.0f) - mu * mu;
  float rstd = rsqrtf(var + 1e-5f);
  float* o = XHo + ((long)b * LL + l) * DD;
  o[tid] = (x0 - mu) * rstd * ldi(g, tid, isf) + ldi(be, tid, isf);
  o[tid + 256] = (x1 - mu) * rstd * ldi(g, tid + 256, isf) + ldi(be, tid + 256, isf);
}

// column-mean partials. grid (2, 8, 32), block 256: part sums 128 rows.
__global__ __launch_bounds__(256) void colmean_k(const float* __restrict__ XHo,
                                                 float* __restrict__ CMp) {
  int d = blockIdx.x * 256 + threadIdx.x;
  int part = blockIdx.y;
  int b = blockIdx.z;
  const float* p = XHo + (long)b * LL * DD + (long)part * 128 * DD + d;
  float s = 0.0f;
  for (int l = 0; l < 128; l++) s += p[(long)l * DD];
  CMp[((long)part * BB + b) * DD + d] = s;
}

// OUT = gelu(XH - mean) * mark. grid (1024,32), block 256
__global__ __launch_bounds__(256) void geluout_k(const float* __restrict__ XHo,
                                                 const float* __restrict__ CMp,
                                                 const void* __restrict__ mark,
                                                 float* __restrict__ OUT,
                                                 const int* __restrict__ FLAG) {
  const int isf = *FLAG;
  int l = blockIdx.x, b = blockIdx.y;
  int tid = threadIdx.x;
  float mk = ldi(mark, (long)b * LL + l, isf);
  long off = ((long)b * LL + l) * DD;
#pragma unroll
  for (int h = 0; h < 2; h++) {
    int d = tid + h * 256;
    float cs = 0.0f;
#pragma unroll
    for (int p = 0; p < 8; p++) cs += CMp[((long)p * BB + b) * DD + d];
    float v = XHo[off + d] - cs * (1.0f / 1024.0f);
    OUT[off + d] = gelu_f(v) * mk;
  }
}

// ---------------------------------------------------------------------------
// proj stage 1 v2: read-once split-K. grid (512), block 256.
// ---------------------------------------------------------------------------
__global__ __launch_bounds__(256) void proj1_k(const float* __restrict__ OUT,
                                               const void* __restrict__ Wp,
                                               float* __restrict__ PB2,
                                               const int* __restrict__ FLAG) {
  const int isf = *FLAG;
  const int blk = blockIdx.x;
  const int tid = threadIdx.x;
  const int wave = tid >> 6, lane = tid & 63;
  const int grp = lane >> 4, ln = lane & 15;
  const long e = (long)blk * 1024 + tid * 4;
  float w[10][4];
  if (isf) {
    const float* wp = (const float*)Wp;
#pragma unroll
    for (int n = 0; n < 10; n++) {
      float4 t = *(const float4*)&wp[(long)n * 524288 + e];
      w[n][0] = t.x; w[n][1] = t.y; w[n][2] = t.z; w[n][3] = t.w;
    }
  } else {
    const u16* wp = (const u16*)Wp;
#pragma unroll
    for (int n = 0; n < 10; n++) {
      uint2 u = *(const uint2*)&wp[(long)n * 524288 + e];
      w[n][0] = bf2f((u16)(u.x & 0xffff));
      w[n][1] = bf2f((u16)(u.x >> 16));
      w[n][2] = bf2f((u16)(u.y & 0xffff));
      w[n][3] = bf2f((u16)(u.y >> 16));
    }
  }
  __shared__ float sm[4][4][BB][16];  // [wave][grp][b][n] = 32 KB
  float4 xn = *(const float4*)&OUT[e];  // prefetch b=0
  for (int b = 0; b < BB; b++) {
    float4 x = xn;
    if (b < BB - 1) xn = *(const float4*)&OUT[(long)(b + 1) * 524288 + e];
    float acc[10];
#pragma unroll
    for (int n = 0; n < 10; n++)
      acc[n] = x.x * w[n][0] + x.y * w[n][1] + x.z * w[n][2] + x.w * w[n][3];
#pragma unroll
    for (int s = 1; s <= 8; s <<= 1)
#pragma unroll
      for (int n = 0; n < 10; n++) acc[n] += __shfl_xor(acc[n], s, 64);
    float v = 0.0f;
#pragma unroll
    for (int n = 0; n < 10; n++) v = (ln == n) ? acc[n] : v;
    if (ln < 10) sm[wave][grp][b][ln] = v;
  }
  __syncthreads();
  for (int o = tid; o < BB * 10; o += 256) {
    int b = o / 10, n = o - b * 10;
    float s = 0.0f;
#pragma unroll
    for (int w4 = 0; w4 < 4; w4++)
#pragma unroll
      for (int g = 0; g < 4; g++) s += sm[w4][g][b][n];
    PB2[(long)o * 512 + blk] = s;
  }
}

// proj stage 2 v2: reduce 512 partials per (b,n). grid (10,32), block 64
__global__ __launch_bounds__(64) void proj2_k(const float* __restrict__ PB2,
                                              const void* __restrict__ bp,
                                              void* __restrict__ out,
                                              const int* __restrict__ FLAG) {
  const int isf = *FLAG;
  int n = blockIdx.x, b = blockIdx.y;
  int o = b * 10 + n;
  int tid = threadIdx.x;
  float s = 0.0f;
  for (int j = tid; j < 512; j += 64) s += PB2[(long)o * 512 + j];
#pragma unroll
  for (int st = 32; st > 0; st >>= 1) s += __shfl_xor(s, st, 64);
  if (tid == 0) {
    s += ldi(bp, n, isf);
    if (isf) ((float*)out)[o] = s;
    else ((u16*)out)[o] = f2bf(s);
  }
}

// ---------------------------------------------------------------------------
extern "C" void kernel_launch(void* const* d_in, const int* in_sizes, int n_in,
                              void* d_out, int out_size, void* d_ws, size_t ws_size,
                              hipStream_t stream) {
  const void* xe = d_in[0];
  const void* mark = d_in[1];
  const void* cw = d_in[2];
  const void* Wq = d_in[3];
  const void* Wk = d_in[5];
  const void* Wv = d_in[7];
  const void* bv = d_in[8];
  const void* Wo = d_in[9];
  const void* bo = d_in[10];
  const void* Wff1 = d_in[11];
  const void* Wff2 = d_in[12];
  const void* lng = d_in[13];
  const void* lnb = d_in[14];
  const void* Wp = d_in[15];
  const void* bp = d_in[16];

  char* ws = (char*)d_ws;
  float* X      = (float*)(ws + 0L);               // 64 MiB f32 residual
  _Float16* XH  = (_Float16*)(ws + 67108864L);     // fp16 X-high, 32 MiB
  _Float16* XL  = (_Float16*)(ws + 100663296L);    // fp16 X-low*512 / AGh
  _Float16* AGh = (_Float16*)(ws + 100663296L);
  _Float16* ZH  = (_Float16*)(ws + 134217728L);    // Z-high chunk, 4 MiB
  _Float16* ZL  = (_Float16*)(ws + 138412032L);    // Z-low chunk, 4 MiB
  _Float16* Ph  = (_Float16*)(ws + 134217728L);    // Phase B: 8 MiB chunk
  float* CMp    = (float*)(ws + 134217728L);       // final: colmean partials
  float* wT     = (float*)(ws + 142606336L);       // conv wT (dead after embed)
  // Phase A overlays (all dead by Phase B):
  _Float16* KTH = (_Float16*)(ws + 142606336L);    // Wk^T split hi, 0.5 MiB
  _Float16* KTL = (_Float16*)(ws + 143130624L);    // Wk^T split lo
  _Float16* QTH = (_Float16*)(ws + 143654912L);    // Wq^T split hi
  _Float16* QTL = (_Float16*)(ws + 144179200L);    // Wq^T split lo
  _Float16* GH  = (_Float16*)(ws + 144703488L);    // G split hi, 0.5 MiB
  _Float16* GL  = (_Float16*)(ws + 145227776L);    // G split lo
  // Phase B overlays:
  _Float16* Wvh = (_Float16*)(ws + 142606336L);
  _Float16* Woh = (_Float16*)(ws + 143130624L);
  _Float16* W1h = (_Float16*)(ws + 143654912L);    // 2 MiB
  _Float16* W2h = (_Float16*)(ws + 145752064L);    // 2 MiB
  float* MV  = (float*)(ws + 147849216L);
  float* WGT = (float*)(ws + 147980288L);
  int*   DLY = (int*)(ws + 147981312L);
  int*  FLAG = (int*)(ws + 148068352L);
  float* S2  = (float*)(ws + 67108864L);           // FFN f32 (spans XH+XL)
  float* PB2 = (float*)(ws + 67108864L);           // proj partials (S2 dead)
  _Float16* Hb = (_Float16*)X;                     // FFN hidden (X dead)

  const long AD = (long)LL * DD;   // 524288
  const int M = BB * LL;           // 32768

  detect_k<<<1, 64, 0, stream>>>((const uint32_t*)mark, FLAG);
  wT_k<<<126, 256, 0, stream>>>(cw, wT, FLAG);
  conv_embed_k<<<dim3(64, 32), 256, 0, stream>>>(xe, wT, X, XH, XL, FLAG);

  for (int l = 0; l < 3; l++) {
    const long oW = (long)l * DD * DD;
    const long oB = (long)l * DD;
    const long oF = (long)l * DFF * DD;

    // ---- Phase A: delay selection via G-trick + fp16x2 split MFMA ----
    tsplit2_k<<<dim3(8, 8, 2), 256, 0, stream>>>(Wk, Wq, oW,
                                                 KTH, KTL, QTH, QTL, FLAG);
    gemm_z<<<dim3(4, 4), 256, 0, stream>>>(KTH, KTL, QTH, QTL,
                                           GH, GL, 512, 512, 512);
    hipMemsetAsync(MV, 0, (long)BB * LL * sizeof(float), stream);
    for (int cb = 0; cb < 8; cb++) {
      const long co = (long)cb * 4 * AD;
      gemm_z<<<dim3(4, 32), 256, 0, stream>>>(
          XH + co, XL + co, GH, GL, ZH, ZL, 4096, DD, DD);
      qkmv_hl<<<dim3(8, 8, 4), 256, 0, stream>>>(
          ZH, ZL, XH + co, XL + co, MV + (long)cb * 4 * LL);
    }
    topk_k<<<32, 256, 0, stream>>>(MV, WGT, DLY);

    // ---- Phase B: fp16 MFMA for V / agg / Wo / FFN ----
    wcvt6_k<<<1280, 256, 0, stream>>>(Wv, Wo, Wff1, Wff2, oW, oF,
                                      Wvh, Woh, W1h, W2h, FLAG);

    // V (fp16) per 8-batch chunk -> Ph (over ZH/ZL, dead), agg -> AGh
    for (int cb = 0; cb < 4; cb++) {
      const _Float16* xh = XH + (long)cb * 8 * AD;
      gemm_h<1 | 8><<<dim3(4, 64), 256, 0, stream>>>(
          xh, Wvh, bv, oB, nullptr, Ph, 8192, DD, DD, FLAG);
      agg_k<<<dim3(1024, 8), 128, 0, stream>>>(
          Ph, WGT + cb * 48, DLY + cb * 48, AGh + (long)cb * 8 * AD);
    }

    // X = X + AGh @ Wo^T + bo (full M, in-place residual)
    gemm_h<1 | 4><<<dim3(4, 256), 256, 0, stream>>>(
        AGh, Woh, bo, oB, X, X, M, DD, DD, FLAG);

    // x = decomp(X) -> S2 f32 (over XH/XL, both dead)
    decomp_k<<<dim3(2, 16, 32), 256, 0, stream>>>(X, S2);

    // FFN per 8-batch chunk: hidden -> Hb (X region, dead);
    // S2chunk = S2chunk + (gelu-hidden) @ W2^T.  FFN1 reads S2 f32 via gld16.
    for (int cb = 0; cb < 4; cb++) {
      float* xd = S2 + (long)cb * 8 * AD;
      gemm_hf<<<dim3(16, 64), 256, 0, stream>>>(
          xd, W1h, Hb, 8192, DFF, DD);
      gemm_h<4><<<dim3(4, 64), 256, 0, stream>>>(
          Hb, W2h, nullptr, 0, xd, xd, 8192, DD, DFF, FLAG);
    }

    // x = decomp(S2) -> X; then split X -> (XH, XL) for next layer
    decomp_k<<<dim3(2, 16, 32), 256, 0, stream>>>(S2, X);
    if (l < 2) split_k<<<8192, 256, 0, stream>>>(X, XH, XL, 16777216);
  }

  // final special layernorm + gelu + mask + projection
  ln_k<<<dim3(1024, 32), 256, 0, stream>>>(X, lng, lnb, S2, FLAG);
  colmean_k<<<dim3(2, 8, 32), 256, 0, stream>>>(S2, CMp);
  geluout_k<<<dim3(1024, 32), 256, 0, stream>>>(S2, CMp, mark, X, FLAG);
  proj1_k<<<512, 256, 0, stream>>>(X, Wp, PB2, FLAG);
  proj2_k<<<dim3(10, 32), 64, 0, stream>>>(PB2, bp, d_out, FLAG);
}

// Round 6
// 3410.895 us; speedup vs baseline: 1.0538x; 1.0538x over previous
//
#include <hip/hip_runtime.h>
#include <cstdint>

// ---------------------------------------------------------------------------
// Autoformer forward — hybrid precision v11 (R16):
//   * R16: 2-phase double-buffered K-loop (T3-min) in gemm_z / qkmv_hl /
//     gemm_hf — issue next-tile global_load_lds BEFORE compute, ONE barrier
//     per K-step. These three are latency-bound (MfmaUtil 12%, occ 20%,
//     1 block/CU for qkmv): the old 2-barrier loop exposed full load
//     latency 16x per kernel. Numerics identical. gemm_h left unchanged
//     (its Wo user needs 4 blocks/CU; 64KB LDS would cliff it — m132).
//   * R15: XCD-aware bijective block swizzle (FETCH 67.8->24.8 MB, verified).
//   * R14a: conv_embed register-caches xs columns.
//   * R13: proj1 read-once split-K; colmean partials.
//   * R11: tsplit2_k + split-fp16 MFMA gemm_z @ 512^3 for G.
// Inputs f32 (runtime-detected from x_mark_enc; bf16 fallback kept).
//
// Workspace (bytes), total ~148.1 MB:
//   X    @ 0          : f32 residual 64Mi; FFN: Hb fp16 hidden (0..32Mi)
//   XH   @ 67108864   : fp16 X-high 32Mi | FFN: S2 f32 64Mi (spans XH+XL!)
//   XL   @ 100663296  : fp16 X-low*512 32Mi / AGh   (S2 second half!)
//   ZH   @ 134217728  : fp16 Z-high chunk 4Mi \ Ph 8Mi (V chunk)
//   ZL   @ 138412032  : fp16 Z-low chunk 4Mi  /  | final: CMp
//   SH   @ 142606336  : Phase A: wT | KTH/KTL/QTH/QTL + GH/GL
//                       Phase B: Wvh/Woh/W1h/W2h
//   MV   @ 147849216, WGT @ 147980288, DLY @ 147981312, FLAG @ 148068352
//   PB2  @ 67108864 (over S2, dead at proj time)
// ---------------------------------------------------------------------------

using u16 = unsigned short;
typedef _Float16 f16x8 __attribute__((ext_vector_type(8)));
typedef float f32x4 __attribute__((ext_vector_type(4)));

#define BB 32
#define LL 1024
#define DD 512
#define DFF 2048

__device__ __forceinline__ float bf2f(u16 u) {
  union { uint32_t i; float f; } v; v.i = ((uint32_t)u) << 16; return v.f;
}
__device__ __forceinline__ u16 f2bf(float f) {
  union { float f; uint32_t i; } v; v.f = f;
  uint32_t r = (v.i + 0x7FFFu + ((v.i >> 16) & 1u)) >> 16;
  return (u16)r;
}
__device__ __forceinline__ float ldi(const void* p, long i, int isf) {
  return isf ? ((const float*)p)[i] : bf2f(((const u16*)p)[i]);
}
__device__ __forceinline__ float gelu_f(float x) {
  return 0.5f * x * (1.0f + erff(x * 0.70710678118654752440f));
}
// async 16B global -> LDS (wave-uniform LDS base + lane*16)
__device__ __forceinline__ void gld16(const void* g, void* l) {
  __builtin_amdgcn_global_load_lds(
      (const __attribute__((address_space(1))) void*)g,
      (__attribute__((address_space(3))) void*)l, 16, 0, 0);
}
// XCD-aware bijective block swizzle (requires nwg % 8 == 0, all grids comply)
__device__ __forceinline__ void swz8(int& bx, int& by) {
  int gx = gridDim.x;
  int nwg = gx * gridDim.y;
  int bid = by * gx + bx;
  int q = nwg >> 3;
  int s = (bid & 7) * q + (bid >> 3);
  bx = s % gx;
  by = s / gx;
}

union H8 { f16x8 v; uint4 u; _Float16 h[8]; };
union H4 { uint2 u; _Float16 h[4]; };

__global__ void detect_k(const uint32_t* __restrict__ mark, int* __restrict__ FLAG) {
  if (threadIdx.x == 0) FLAG[0] = (mark[0] == 0x3F800000u) ? 1 : 0;
}

// transpose conv weight to wT[(c*3+t)*512 + d], f32. grid 126, block 256
__global__ __launch_bounds__(256) void wT_k(const void* __restrict__ w,
                                            float* __restrict__ wT,
                                            const int* __restrict__ FLAG) {
  const int isf = *FLAG;
  int idx = blockIdx.x * 256 + threadIdx.x;
  if (idx >= 63 * DD) return;
  int c3t = idx / DD;
  int d = idx - c3t * DD;
  wT[idx] = ldi(w, (long)d * 63 + c3t, isf);
}

// ---------------------------------------------------------------------------
// Conv1d circular embedding + fused split. grid (L/16, B), block 256.
// ---------------------------------------------------------------------------
__global__ __launch_bounds__(256) void conv_embed_k(
    const void* __restrict__ xe, const float* __restrict__ wT,
    float* __restrict__ X, _Float16* __restrict__ XH, _Float16* __restrict__ XL,
    const int* __restrict__ FLAG) {
  const int isf = *FLAG;
  int b = blockIdx.y;
  int l0 = blockIdx.x * 16;
  __shared__ float xs[18][21];
  int tid = threadIdx.x;
  for (int i = tid; i < 18 * 21; i += 256) {
    int r = i / 21, c = i % 21;
    int row = (l0 - 1 + r + LL) & (LL - 1);
    xs[r][c] = ldi(xe, ((long)b * LL + row) * 21 + c, isf);
  }
  __syncthreads();
  float acc0[16], acc1[16];
#pragma unroll
  for (int ll = 0; ll < 16; ll++) { acc0[ll] = 0.0f; acc1[ll] = 0.0f; }
  for (int c = 0; c < 21; c++) {
    float xreg[18];
#pragma unroll
    for (int r = 0; r < 18; r++) xreg[r] = xs[r][c];
#pragma unroll
    for (int t = 0; t < 3; t++) {
      float w0 = wT[(c * 3 + t) * DD + tid];
      float w1 = wT[(c * 3 + t) * DD + tid + 256];
#pragma unroll
      for (int ll = 0; ll < 16; ll++) {
        acc0[ll] = fmaf(w0, xreg[t + ll], acc0[ll]);
        acc1[ll] = fmaf(w1, xreg[t + ll], acc1[ll]);
      }
    }
  }
#pragma unroll
  for (int ll = 0; ll < 16; ll++) {
    long base = ((long)b * LL + l0 + ll) * DD;
    float v0 = acc0[ll], v1 = acc1[ll];
    X[base + tid] = v0;
    X[base + tid + 256] = v1;
    _Float16 h0 = (_Float16)v0, h1 = (_Float16)v1;
    XH[base + tid] = h0;
    XH[base + tid + 256] = h1;
    XL[base + tid] = (_Float16)((v0 - (float)h0) * 512.0f);
    XL[base + tid + 256] = (_Float16)((v1 - (float)h1) * 512.0f);
  }
}

// ---------------------------------------------------------------------------
// transpose + split BOTH Wq/Wk in one launch. grid (8, 8, 2), block 256.
// ---------------------------------------------------------------------------
__global__ __launch_bounds__(256) void tsplit2_k(
    const void* __restrict__ W1, const void* __restrict__ W2, long off,
    _Float16* __restrict__ T1H, _Float16* __restrict__ T1L,
    _Float16* __restrict__ T2H, _Float16* __restrict__ T2L,
    const int* __restrict__ FLAG) {
  const int isf = *FLAG;
  const void* W = blockIdx.z ? W2 : W1;
  _Float16* TH = blockIdx.z ? T2H : T1H;
  _Float16* TL = blockIdx.z ? T2L : T1L;
  __shared__ float t[64][65];
  const int f0 = blockIdx.x * 64, m0 = blockIdx.y * 64;
  const int tid = threadIdx.x;
  const int c = tid & 63, rb = tid >> 6;
#pragma unroll
  for (int r = rb; r < 64; r += 4)
    t[r][c] = ldi(W, off + (long)(f0 + r) * DD + m0 + c, isf);
  __syncthreads();
#pragma unroll
  for (int r = rb; r < 64; r += 4) {
    float v = t[c][r];
    long o = (long)(m0 + r) * DD + f0 + c;
    _Float16 hv = (_Float16)v;
    TH[o] = hv;
    TL[o] = (_Float16)((v - (float)hv) * 512.0f);
  }
}

// split f32 -> (fp16 high, fp16 low*512). 8 elems/thread.
__global__ __launch_bounds__(256) void split_k(const float* __restrict__ src,
                                               _Float16* __restrict__ dh,
                                               _Float16* __restrict__ dl, int n) {
  long i = ((long)blockIdx.x * 256 + threadIdx.x) * 8;
  if (i >= n) return;
  float4 a = *(const float4*)(src + i);
  float4 b = *(const float4*)(src + i + 4);
  float x[8] = {a.x, a.y, a.z, a.w, b.x, b.y, b.z, b.w};
  H8 h, l;
#pragma unroll
  for (int j = 0; j < 8; j++) {
    _Float16 hv = (_Float16)x[j];
    h.h[j] = hv;
    l.h[j] = (_Float16)((x[j] - (float)hv) * 512.0f);
  }
  *(uint4*)(dh + i) = h.u;
  *(uint4*)(dl + i) = l.u;
}

// all four Phase-B weights -> fp16 in one launch. grid 1280, block 256
__global__ __launch_bounds__(256) void wcvt6_k(
    const void* __restrict__ Wv, const void* __restrict__ Wo,
    const void* __restrict__ W1, const void* __restrict__ W2,
    long oW, long oF,
    _Float16* __restrict__ Wvh, _Float16* __restrict__ Woh,
    _Float16* __restrict__ W1h, _Float16* __restrict__ W2h,
    const int* __restrict__ FLAG) {
  const int isf = *FLAG;
  long e = ((long)blockIdx.x * 256 + threadIdx.x) * 8;
  const void* src; long soff; _Float16* dst;
  if (e < 262144) { src = Wv; soff = oW + e; dst = Wvh + e; }
  else if (e < 524288) { src = Wo; soff = oW + (e - 262144); dst = Woh + (e - 262144); }
  else if (e < 1572864) { src = W1; soff = oF + (e - 524288); dst = W1h + (e - 524288); }
  else { src = W2; soff = oF + (e - 1572864); dst = W2h + (e - 1572864); }
  H8 r;
  if (isf) {
    const float* s = (const float*)src + soff;
    float4 a = *(const float4*)s;
    float4 b = *(const float4*)(s + 4);
    r.h[0] = (_Float16)a.x; r.h[1] = (_Float16)a.y;
    r.h[2] = (_Float16)a.z; r.h[3] = (_Float16)a.w;
    r.h[4] = (_Float16)b.x; r.h[5] = (_Float16)b.y;
    r.h[6] = (_Float16)b.z; r.h[7] = (_Float16)b.w;
  } else {
    const u16* s = (const u16*)src + soff;
    uint4 u = *(const uint4*)s;
    r.h[0] = (_Float16)bf2f((u16)(u.x & 0xffff));
    r.h[1] = (_Float16)bf2f((u16)(u.x >> 16));
    r.h[2] = (_Float16)bf2f((u16)(u.y & 0xffff));
    r.h[3] = (_Float16)bf2f((u16)(u.y >> 16));
    r.h[4] = (_Float16)bf2f((u16)(u.z & 0xffff));
    r.h[5] = (_Float16)bf2f((u16)(u.z >> 16));
    r.h[6] = (_Float16)bf2f((u16)(u.w & 0xffff));
    r.h[7] = (_Float16)bf2f((u16)(u.w >> 16));
  }
  *(uint4*)(dst) = r.u;
}

// ---------------------------------------------------------------------------
// split-fp16 MFMA GEMM: Z = A @ W^T (split in/out). BK=32.
// R16: 2-phase double-buffered (prefetch next K-tile before compute,
// one barrier per step). Numerics identical to R9-verified version.
// ---------------------------------------------------------------------------
__global__ __launch_bounds__(256) void gemm_z(
    const _Float16* __restrict__ Ah, const _Float16* __restrict__ Al,
    const _Float16* __restrict__ Bh, const _Float16* __restrict__ Bl,
    _Float16* __restrict__ Zh, _Float16* __restrict__ Zl,
    int M, int N, int K) {
  __shared__ __align__(16) _Float16 AsH[2][128 * 32];
  __shared__ __align__(16) _Float16 AsL[2][128 * 32];
  __shared__ __align__(16) _Float16 BsH[2][128 * 32];
  __shared__ __align__(16) _Float16 BsL[2][128 * 32];
  int bx = blockIdx.x, by = blockIdx.y;
  swz8(bx, by);
  const int n0 = bx * 128, m0 = by * 128;
  const int tid = threadIdx.x;
  const int lane = tid & 63, wvi = tid >> 6;
  const int wm = (wvi >> 1) * 64, wn = (wvi & 1) * 64;
  const int l15 = lane & 15, quad = lane >> 4;
  const int ib = wvi * 128 + lane;
  const int r0 = ib >> 2, r1 = r0 + 16;
  const int c0 = ((ib & 3) ^ ((r0 >> 1) & 3)) * 8;
  const int c1 = ((ib & 3) ^ ((r1 >> 1) & 3)) * 8;
  const int lb0 = wvi * 1024, lb1 = wvi * 1024 + 512;
  const long ga0 = (long)(m0 + r0) * K + c0;
  const long ga1 = (long)(m0 + r1) * K + c1;
  const long gb0 = (long)(n0 + r0) * K + c0;
  const long gb1 = (long)(n0 + r1) * K + c1;
  f32x4 aM[4][4], aC[4][4];
#pragma unroll
  for (int i = 0; i < 4; i++)
#pragma unroll
    for (int j = 0; j < 4; j++) {
      aM[i][j] = (f32x4){0.f, 0.f, 0.f, 0.f};
      aC[i][j] = (f32x4){0.f, 0.f, 0.f, 0.f};
    }
  // prologue: stage tile 0 into buffer 0
  gld16(Ah + ga0, AsH[0] + lb0);
  gld16(Ah + ga1, AsH[0] + lb1);
  gld16(Al + ga0, AsL[0] + lb0);
  gld16(Al + ga1, AsL[0] + lb1);
  gld16(Bh + gb0, BsH[0] + lb0);
  gld16(Bh + gb1, BsH[0] + lb1);
  gld16(Bl + gb0, BsL[0] + lb0);
  gld16(Bl + gb1, BsL[0] + lb1);
  __syncthreads();
  int cur = 0;
  for (int k0 = 0; k0 < K; k0 += 32) {
    const int kn = k0 + 32;
    if (kn < K) {  // prefetch next tile into the other buffer
      gld16(Ah + ga0 + kn, AsH[cur ^ 1] + lb0);
      gld16(Ah + ga1 + kn, AsH[cur ^ 1] + lb1);
      gld16(Al + ga0 + kn, AsL[cur ^ 1] + lb0);
      gld16(Al + ga1 + kn, AsL[cur ^ 1] + lb1);
      gld16(Bh + gb0 + kn, BsH[cur ^ 1] + lb0);
      gld16(Bh + gb1 + kn, BsH[cur ^ 1] + lb1);
      gld16(Bl + gb0 + kn, BsL[cur ^ 1] + lb0);
      gld16(Bl + gb1 + kn, BsL[cur ^ 1] + lb1);
    }
    f16x8 fah[4], fal[4], fbh[4], fbl[4];
#pragma unroll
    for (int mi = 0; mi < 4; mi++) {
      int r = wm + mi * 16 + l15;
      int o = r * 32 + ((quad ^ ((r >> 1) & 3)) * 8);
      fah[mi] = *(const f16x8*)&AsH[cur][o];
      fal[mi] = *(const f16x8*)&AsL[cur][o];
    }
#pragma unroll
    for (int ni = 0; ni < 4; ni++) {
      int r = wn + ni * 16 + l15;
      int o = r * 32 + ((quad ^ ((r >> 1) & 3)) * 8);
      fbh[ni] = *(const f16x8*)&BsH[cur][o];
      fbl[ni] = *(const f16x8*)&BsL[cur][o];
    }
#pragma unroll
    for (int mi = 0; mi < 4; mi++)
#pragma unroll
      for (int ni = 0; ni < 4; ni++) {
        aM[mi][ni] = __builtin_amdgcn_mfma_f32_16x16x32_f16(
            fah[mi], fbh[ni], aM[mi][ni], 0, 0, 0);
        aC[mi][ni] = __builtin_amdgcn_mfma_f32_16x16x32_f16(
            fah[mi], fbl[ni], aC[mi][ni], 0, 0, 0);
        aC[mi][ni] = __builtin_amdgcn_mfma_f32_16x16x32_f16(
            fal[mi], fbh[ni], aC[mi][ni], 0, 0, 0);
      }
    __syncthreads();  // drains prefetch (vmcnt 0) + guards buffer reuse
    cur ^= 1;
  }
#pragma unroll
  for (int mi = 0; mi < 4; mi++) {
    int rowg = m0 + wm + mi * 16 + quad * 4;
#pragma unroll
    for (int ni = 0; ni < 4; ni++) {
      int colg = n0 + wn + ni * 16 + l15;
#pragma unroll
      for (int rr = 0; rr < 4; rr++) {
        long off = (long)(rowg + rr) * N + colg;
        float z = aM[mi][ni][rr] + aC[mi][ni][rr] * (1.0f / 512.0f);
        _Float16 zh = (_Float16)z;
        Zh[off] = zh;
        Zl[off] = (_Float16)((z - (float)zh) * 512.0f);
      }
    }
  }
}

// ---------------------------------------------------------------------------
// split-fp16 MFMA Z.X^T + fused wrapped-diagonal mean reduce. BK=32.
// R16: 2-phase double-buffered (same transformation as gemm_z).
// ---------------------------------------------------------------------------
__global__ __launch_bounds__(256) void qkmv_hl(
    const _Float16* __restrict__ Zh, const _Float16* __restrict__ Zl,
    const _Float16* __restrict__ Xh, const _Float16* __restrict__ Xl,
    float* __restrict__ MV) {
  __shared__ __align__(16) _Float16 AsH[2][128 * 32];
  __shared__ __align__(16) _Float16 AsL[2][128 * 32];
  __shared__ __align__(16) _Float16 BsH[2][128 * 32];
  __shared__ __align__(16) _Float16 BsL[2][128 * 32];
  __shared__ float diag[255];
  const int bz = blockIdx.z;
  const long bb = (long)bz * LL * DD;
  const int n0 = blockIdx.x * 128, m0 = blockIdx.y * 128;
  const int tid = threadIdx.x;
  const int lane = tid & 63, wvi = tid >> 6;
  const int wm = (wvi >> 1) * 64, wn = (wvi & 1) * 64;
  const int l15 = lane & 15, quad = lane >> 4;
  const int ib = wvi * 128 + lane;
  const int r0 = ib >> 2, r1 = r0 + 16;
  const int c0 = ((ib & 3) ^ ((r0 >> 1) & 3)) * 8;
  const int c1 = ((ib & 3) ^ ((r1 >> 1) & 3)) * 8;
  const int lb0 = wvi * 1024, lb1 = wvi * 1024 + 512;
  const long ga0 = bb + (long)(m0 + r0) * DD + c0;
  const long ga1 = bb + (long)(m0 + r1) * DD + c1;
  const long gb0 = bb + (long)(n0 + r0) * DD + c0;
  const long gb1 = bb + (long)(n0 + r1) * DD + c1;
  if (tid < 255) diag[tid] = 0.0f;
  f32x4 aM[4][4], aC[4][4];
#pragma unroll
  for (int i = 0; i < 4; i++)
#pragma unroll
    for (int j = 0; j < 4; j++) {
      aM[i][j] = (f32x4){0.f, 0.f, 0.f, 0.f};
      aC[i][j] = (f32x4){0.f, 0.f, 0.f, 0.f};
    }
  // prologue
  gld16(Zh + ga0, AsH[0] + lb0);
  gld16(Zh + ga1, AsH[0] + lb1);
  gld16(Zl + ga0, AsL[0] + lb0);
  gld16(Zl + ga1, AsL[0] + lb1);
  gld16(Xh + gb0, BsH[0] + lb0);
  gld16(Xh + gb1, BsH[0] + lb1);
  gld16(Xl + gb0, BsL[0] + lb0);
  gld16(Xl + gb1, BsL[0] + lb1);
  __syncthreads();
  int cur = 0;
  for (int k0 = 0; k0 < DD; k0 += 32) {
    const int kn = k0 + 32;
    if (kn < DD) {
      gld16(Zh + ga0 + kn, AsH[cur ^ 1] + lb0);
      gld16(Zh + ga1 + kn, AsH[cur ^ 1] + lb1);
      gld16(Zl + ga0 + kn, AsL[cur ^ 1] + lb0);
      gld16(Zl + ga1 + kn, AsL[cur ^ 1] + lb1);
      gld16(Xh + gb0 + kn, BsH[cur ^ 1] + lb0);
      gld16(Xh + gb1 + kn, BsH[cur ^ 1] + lb1);
      gld16(Xl + gb0 + kn, BsL[cur ^ 1] + lb0);
      gld16(Xl + gb1 + kn, BsL[cur ^ 1] + lb1);
    }
    f16x8 fah[4], fal[4], fbh[4], fbl[4];
#pragma unroll
    for (int mi = 0; mi < 4; mi++) {
      int r = wm + mi * 16 + l15;
      int o = r * 32 + ((quad ^ ((r >> 1) & 3)) * 8);
      fah[mi] = *(const f16x8*)&AsH[cur][o];
      fal[mi] = *(const f16x8*)&AsL[cur][o];
    }
#pragma unroll
    for (int ni = 0; ni < 4; ni++) {
      int r = wn + ni * 16 + l15;
      int o = r * 32 + ((quad ^ ((r >> 1) & 3)) * 8);
      fbh[ni] = *(const f16x8*)&BsH[cur][o];
      fbl[ni] = *(const f16x8*)&BsL[cur][o];
    }
#pragma unroll
    for (int mi = 0; mi < 4; mi++)
#pragma unroll
      for (int ni = 0; ni < 4; ni++) {
        aM[mi][ni] = __builtin_amdgcn_mfma_f32_16x16x32_f16(
            fah[mi], fbh[ni], aM[mi][ni], 0, 0, 0);
        aC[mi][ni] = __builtin_amdgcn_mfma_f32_16x16x32_f16(
            fah[mi], fbl[ni], aC[mi][ni], 0, 0, 0);
        aC[mi][ni] = __builtin_amdgcn_mfma_f32_16x16x32_f16(
            fal[mi], fbh[ni], aC[mi][ni], 0, 0, 0);
      }
    __syncthreads();
    cur ^= 1;
  }
#pragma unroll
  for (int g = -3; g <= 3; g++) {
#pragma unroll
    for (int rr = 0; rr < 4; rr++) {
      float s = 0.0f;
#pragma unroll
      for (int mi = 0; mi < 4; mi++) {
        int ni = mi - g;
        if (ni >= 0 && ni < 4)
          s += aM[mi][ni][rr] + aC[mi][ni][rr] * (1.0f / 512.0f);
      }
      int d = 127 + (wm - wn) + g * 16 + quad * 4 + rr - l15;
      atomicAdd(&diag[d], s);
    }
  }
  __syncthreads();
  if (tid < 255) {
    int tau = (m0 - n0 + tid - 127 + LL) & (LL - 1);
    atomicAdd(&MV[(long)bz * LL + tau], diag[tid] * (1.0f / 512.0f));
  }
}

// ---------------------------------------------------------------------------
// fp16 MFMA GEMM, BK=64: C[M,N] = act( A[M,K] @ W[N,K]^T + bias + R )
// FLAGS: 1=bias 2=gelu 4=residual 8=out-fp16
// ---------------------------------------------------------------------------
template <int FLAGS>
__global__ __launch_bounds__(256) void gemm_h(
    const _Float16* __restrict__ A, const _Float16* __restrict__ W,
    const void* __restrict__ biasBase, long bOff,
    const float* __restrict__ R, void* __restrict__ Cout,
    int M, int N, int K, const int* __restrict__ FLAG) {
  constexpr bool HAS_BIAS = (FLAGS & 1) != 0;
  constexpr bool DO_GELU = (FLAGS & 2) != 0;
  constexpr bool DO_RES = (FLAGS & 4) != 0;
  constexpr bool OUT_H = (FLAGS & 8) != 0;
  __shared__ __align__(16) _Float16 As[128 * 64];
  __shared__ __align__(16) _Float16 Bs[128 * 64];
  int bx = blockIdx.x, by = blockIdx.y;
  swz8(bx, by);
  const int n0 = bx * 128, m0 = by * 128;
  const int tid = threadIdx.x;
  const int lane = tid & 63, wvi = tid >> 6;
  const int wm = (wvi >> 1) * 64, wn = (wvi & 1) * 64;
  const int l15 = lane & 15, quad = lane >> 4;
  const _Float16* gA[4];
  const _Float16* gB[4];
  int ldsOff[4];
#pragma unroll
  for (int j = 0; j < 4; j++) {
    int ib = wvi * 256 + j * 64 + lane;
    int row = ib >> 3, p = ib & 7;
    int gc = ((p & 4) | ((p & 3) ^ ((row >> 1) & 3))) * 8;
    gA[j] = A + (long)(m0 + row) * K + gc;
    gB[j] = W + (long)(n0 + row) * K + gc;
    ldsOff[j] = wvi * 2048 + j * 512;
  }
  f32x4 acc[4][4];
#pragma unroll
  for (int i = 0; i < 4; i++)
#pragma unroll
    for (int j = 0; j < 4; j++) acc[i][j] = (f32x4){0.f, 0.f, 0.f, 0.f};
  for (int k0 = 0; k0 < K; k0 += 64) {
    __syncthreads();
#pragma unroll
    for (int j = 0; j < 4; j++) gld16(gA[j] + k0, As + ldsOff[j]);
#pragma unroll
    for (int j = 0; j < 4; j++) gld16(gB[j] + k0, Bs + ldsOff[j]);
    __syncthreads();
#pragma unroll
    for (int ks = 0; ks < 2; ks++) {
      f16x8 af[4], bfr[4];
#pragma unroll
      for (int mi = 0; mi < 4; mi++) {
        int r = wm + mi * 16 + l15;
        af[mi] = *(const f16x8*)&As[r * 64 + (ks * 4 + (quad ^ ((r >> 1) & 3))) * 8];
      }
#pragma unroll
      for (int ni = 0; ni < 4; ni++) {
        int r = wn + ni * 16 + l15;
        bfr[ni] = *(const f16x8*)&Bs[r * 64 + (ks * 4 + (quad ^ ((r >> 1) & 3))) * 8];
      }
#pragma unroll
      for (int mi = 0; mi < 4; mi++)
#pragma unroll
        for (int ni = 0; ni < 4; ni++)
          acc[mi][ni] = __builtin_amdgcn_mfma_f32_16x16x32_f16(
              af[mi], bfr[ni], acc[mi][ni], 0, 0, 0);
    }
  }
  float bcol[4];
  if constexpr (HAS_BIAS) {
    const int isf = *FLAG;
#pragma unroll
    for (int ni = 0; ni < 4; ni++)
      bcol[ni] = ldi(biasBase, bOff + n0 + wn + ni * 16 + l15, isf);
  }
#pragma unroll
  for (int mi = 0; mi < 4; mi++) {
    int rowg = m0 + wm + mi * 16 + quad * 4;
#pragma unroll
    for (int ni = 0; ni < 4; ni++) {
      int colg = n0 + wn + ni * 16 + l15;
#pragma unroll
      for (int rr = 0; rr < 4; rr++) {
        long off = (long)(rowg + rr) * N + colg;
        float v = acc[mi][ni][rr];
        if constexpr (HAS_BIAS) v += bcol[ni];
        if constexpr (DO_RES) v += R[off];
        if constexpr (DO_GELU) v = gelu_f(v);
        if constexpr (OUT_H) ((_Float16*)Cout)[off] = (_Float16)v;
        else ((float*)Cout)[off] = v;
      }
    }
  }
}

// ---------------------------------------------------------------------------
// FFN1 GEMM: C[M,N] = gelu(Af32[M,K] @ W[N,K]^T) -> fp16. BK=32.
// A staged as f32 via global_load_lds, cvt->fp16 on fragment read.
// R16: 2-phase double-buffered.
// ---------------------------------------------------------------------------
__global__ __launch_bounds__(256) void gemm_hf(
    const float* __restrict__ A, const _Float16* __restrict__ W,
    _Float16* __restrict__ Cout, int M, int N, int K) {
  __shared__ __align__(16) float As32[2][128 * 32];   // 32 KB
  __shared__ __align__(16) _Float16 Bs[2][128 * 32];  // 16 KB
  int bx = blockIdx.x, by = blockIdx.y;
  swz8(bx, by);
  const int n0 = bx * 128, m0 = by * 128;
  const int tid = threadIdx.x;
  const int lane = tid & 63, wvi = tid >> 6;
  const int wm = (wvi >> 1) * 64, wn = (wvi & 1) * 64;
  const int l15 = lane & 15, quad = lane >> 4;
  // A staging: slot ib = j*256+tid -> row ib>>3, seg p = ib&7,
  // global seg gs = p ^ (row&7). LDS dst linear (wave base + lane*16).
  const float* gAf[4];
#pragma unroll
  for (int j = 0; j < 4; j++) {
    int ib = j * 256 + tid;
    int row = ib >> 3, p = ib & 7;
    int gs = p ^ (row & 7);
    gAf[j] = A + (long)(m0 + row) * K + gs * 4;
  }
  // B staging: gemm_z pattern
  const int ibb = wvi * 128 + lane;
  const int r0 = ibb >> 2, r1 = r0 + 16;
  const int c0 = ((ibb & 3) ^ ((r0 >> 1) & 3)) * 8;
  const int c1 = ((ibb & 3) ^ ((r1 >> 1) & 3)) * 8;
  const int lb0 = wvi * 1024, lb1 = wvi * 1024 + 512;
  const long gb0 = (long)(n0 + r0) * K + c0;
  const long gb1 = (long)(n0 + r1) * K + c1;
  f32x4 acc[4][4];
#pragma unroll
  for (int i = 0; i < 4; i++)
#pragma unroll
    for (int j = 0; j < 4; j++) acc[i][j] = (f32x4){0.f, 0.f, 0.f, 0.f};
  // prologue
#pragma unroll
  for (int j = 0; j < 4; j++)
    gld16(gAf[j], As32[0] + j * 1024 + wvi * 256);
  gld16(W + gb0, Bs[0] + lb0);
  gld16(W + gb1, Bs[0] + lb1);
  __syncthreads();
  int cur = 0;
  for (int k0 = 0; k0 < K; k0 += 32) {
    const int kn = k0 + 32;
    if (kn < K) {
#pragma unroll
      for (int j = 0; j < 4; j++)
        gld16(gAf[j] + kn, As32[cur ^ 1] + j * 1024 + wvi * 256);
      gld16(W + gb0 + kn, Bs[cur ^ 1] + lb0);
      gld16(W + gb1 + kn, Bs[cur ^ 1] + lb1);
    }
    f16x8 af[4], bf[4];
#pragma unroll
    for (int mi = 0; mi < 4; mi++) {
      int r = wm + mi * 16 + l15;
      int p0 = (2 * quad) ^ (r & 7);
      int p1 = (2 * quad + 1) ^ (r & 7);
      f32x4 v0 = *(const f32x4*)&As32[cur][r * 32 + p0 * 4];
      f32x4 v1 = *(const f32x4*)&As32[cur][r * 32 + p1 * 4];
      H8 h;
      h.h[0] = (_Float16)v0[0]; h.h[1] = (_Float16)v0[1];
      h.h[2] = (_Float16)v0[2]; h.h[3] = (_Float16)v0[3];
      h.h[4] = (_Float16)v1[0]; h.h[5] = (_Float16)v1[1];
      h.h[6] = (_Float16)v1[2]; h.h[7] = (_Float16)v1[3];
      af[mi] = h.v;
    }
#pragma unroll
    for (int ni = 0; ni < 4; ni++) {
      int r = wn + ni * 16 + l15;
      int o = r * 32 + ((quad ^ ((r >> 1) & 3)) * 8);
      bf[ni] = *(const f16x8*)&Bs[cur][o];
    }
#pragma unroll
    for (int mi = 0; mi < 4; mi++)
#pragma unroll
      for (int ni = 0; ni < 4; ni++)
        acc[mi][ni] = __builtin_amdgcn_mfma_f32_16x16x32_f16(
            af[mi], bf[ni], acc[mi][ni], 0, 0, 0);
    __syncthreads();
    cur ^= 1;
  }
#pragma unroll
  for (int mi = 0; mi < 4; mi++) {
    int rowg = m0 + wm + mi * 16 + quad * 4;
#pragma unroll
    for (int ni = 0; ni < 4; ni++) {
      int colg = n0 + wn + ni * 16 + l15;
#pragma unroll
      for (int rr = 0; rr < 4; rr++) {
        float v = gelu_f(acc[mi][ni][rr]);
        Cout[(long)(rowg + rr) * N + colg] = (_Float16)v;
      }
    }
  }
}

// ---------------------------------------------------------------------------
// top-6 of MV[b,:] + softmax.  grid (32), block 256
// ---------------------------------------------------------------------------
__global__ __launch_bounds__(256) void topk_k(const float* __restrict__ MV,
                                              float* __restrict__ WGT,
                                              int* __restrict__ DLY) {
  int b = blockIdx.x;
  __shared__ float vals[LL];
  __shared__ float rv[256];
  __shared__ int ri[256];
  __shared__ float selv[6];
  int tid = threadIdx.x;
  for (int i = tid; i < LL; i += 256) vals[i] = MV[(long)b * LL + i];
  __syncthreads();
  for (int it = 0; it < 6; it++) {
    float bv = -1e30f;
    int bi = LL - 1;
    for (int i = tid; i < LL; i += 256) {
      float v = vals[i];
      if (v > bv || (v == bv && i < bi)) { bv = v; bi = i; }
    }
    rv[tid] = bv; ri[tid] = bi;
    __syncthreads();
    for (int st = 128; st > 0; st >>= 1) {
      if (tid < st) {
        float ov = rv[tid + st]; int oi = ri[tid + st];
        if (ov > rv[tid] || (ov == rv[tid] && oi < ri[tid])) {
          rv[tid] = ov; ri[tid] = oi;
        }
      }
      __syncthreads();
    }
    if (tid == 0) {
      selv[it] = rv[0];
      DLY[b * 6 + it] = ri[0];
      vals[ri[0]] = -1e30f;
    }
    __syncthreads();
  }
  if (tid == 0) {
    float mx = selv[0];
    float e[6], s = 0.0f;
    for (int i = 0; i < 6; i++) { e[i] = expf(selv[i] - mx); s += e[i]; }
    for (int i = 0; i < 6; i++) WGT[b * 6 + i] = e[i] / s;
  }
}

// ---------------------------------------------------------------------------
// time-delay aggregation, fp16 in/out (chunk-local): grid (1024, NB), block 128
// ---------------------------------------------------------------------------
__global__ __launch_bounds__(128) void agg_k(const _Float16* __restrict__ V,
                                             const float* __restrict__ WGT,
                                             const int* __restrict__ DLY,
                                             _Float16* __restrict__ O) {
  int l = blockIdx.x, b = blockIdx.y;
  int tid = threadIdx.x;
  float w[6]; int dl[6];
#pragma unroll
  for (int i = 0; i < 6; i++) { w[i] = WGT[b * 6 + i]; dl[i] = DLY[b * 6 + i]; }
  long base = (long)b * LL * DD;
  int d = tid * 4;
  float a0 = 0, a1 = 0, a2 = 0, a3 = 0;
#pragma unroll
  for (int i = 0; i < 6; i++) {
    int row = (l + dl[i]) & (LL - 1);
    H4 t; t.u = *(const uint2*)&V[base + (long)row * DD + d];
    a0 += w[i] * (float)t.h[0];
    a1 += w[i] * (float)t.h[1];
    a2 += w[i] * (float)t.h[2];
    a3 += w[i] * (float)t.h[3];
  }
  H4 r;
  r.h[0] = (_Float16)a0; r.h[1] = (_Float16)a1;
  r.h[2] = (_Float16)a2; r.h[3] = (_Float16)a3;
  *(uint2*)&O[base + (long)l * DD + d] = r.u;
}

// ---------------------------------------------------------------------------
// series_decomp residual (f32 out only, race-free). grid (2, 16, 32), block 256
// ---------------------------------------------------------------------------
__global__ __launch_bounds__(256) void decomp_k(const float* __restrict__ Xin,
                                                float* __restrict__ Out) {
  int d = blockIdx.x * 256 + threadIdx.x;
  int l0 = blockIdx.y * 64;
  int b = blockIdx.z;
  const float* xb = Xin + (long)b * LL * DD + d;
  float* ob = Out + (long)b * LL * DD + d;
  float wsum = 0.0f;
  for (int j = l0 - 12; j <= l0 + 12; j++) {
    int jj = min(max(j, 0), LL - 1);
    wsum += xb[(long)jj * DD];
  }
  for (int l = l0; l < l0 + 64; l++) {
    float xv = xb[(long)l * DD];
    ob[(long)l * DD] = xv - wsum * (1.0f / 25.0f);
    int ja = min(l + 13, LL - 1);
    int jr = max(l - 12, 0);
    wsum += xb[(long)ja * DD] - xb[(long)jr * DD];
  }
}

// special layernorm. grid (1024,32), block 256
__global__ __launch_bounds__(256) void ln_k(const float* __restrict__ X,
                                            const void* __restrict__ g,
                                            const void* __restrict__ be,
                                            float* __restrict__ XHo,
                                            const int* __restrict__ FLAG) {
  const int isf = *FLAG;
  int l = blockIdx.x, b = blockIdx.y;
  const float* xr = X + ((long)b * LL + l) * DD;
  int tid = threadIdx.x;
  float x0 = xr[tid], x1 = xr[tid + 256];
  __shared__ float rs[256], rq[256];
  rs[tid] = x0 + x1;
  rq[tid] = x0 * x0 + x1 * x1;
  __syncthreads();
  for (int st = 128; st > 0; st >>= 1) {
    if (tid < st) { rs[tid] += rs[tid + st]; rq[tid] += rq[tid + st]; }
    __syncthreads();
  }
  float mu = rs[0] * (1.0f / 512.0f);
  float var = rq[0] * (1.0f / 512.0f) - mu * mu;
  float rstd = rsqrtf(var + 1e-5f);
  float* o = XHo + ((long)b * LL + l) * DD;
  o[tid] = (x0 - mu) * rstd * ldi(g, tid, isf) + ldi(be, tid, isf);
  o[tid + 256] = (x1 - mu) * rstd * ldi(g, tid + 256, isf) + ldi(be, tid + 256, isf);
}

// column-mean partials. grid (2, 8, 32), block 256: part sums 128 rows.
__global__ __launch_bounds__(256) void colmean_k(const float* __restrict__ XHo,
                                                 float* __restrict__ CMp) {
  int d = blockIdx.x * 256 + threadIdx.x;
  int part = blockIdx.y;
  int b = blockIdx.z;
  const float* p = XHo + (long)b * LL * DD + (long)part * 128 * DD + d;
  float s = 0.0f;
  for (int l = 0; l < 128; l++) s += p[(long)l * DD];
  CMp[((long)part * BB + b) * DD + d] = s;
}

// OUT = gelu(XH - mean) * mark. grid (1024,32), block 256
__global__ __launch_bounds__(256) void geluout_k(const float* __restrict__ XHo,
                                                 const float* __restrict__ CMp,
                                                 const void* __restrict__ mark,
                                                 float* __restrict__ OUT,
                                                 const int* __restrict__ FLAG) {
  const int isf = *FLAG;
  int l = blockIdx.x, b = blockIdx.y;
  int tid = threadIdx.x;
  float mk = ldi(mark, (long)b * LL + l, isf);
  long off = ((long)b * LL + l) * DD;
#pragma unroll
  for (int h = 0; h < 2; h++) {
    int d = tid + h * 256;
    float cs = 0.0f;
#pragma unroll
    for (int p = 0; p < 8; p++) cs += CMp[((long)p * BB + b) * DD + d];
    float v = XHo[off + d] - cs * (1.0f / 1024.0f);
    OUT[off + d] = gelu_f(v) * mk;
  }
}

// ---------------------------------------------------------------------------
// proj stage 1 v2: read-once split-K. grid (512), block 256.
// ---------------------------------------------------------------------------
__global__ __launch_bounds__(256) void proj1_k(const float* __restrict__ OUT,
                                               const void* __restrict__ Wp,
                                               float* __restrict__ PB2,
                                               const int* __restrict__ FLAG) {
  const int isf = *FLAG;
  const int blk = blockIdx.x;
  const int tid = threadIdx.x;
  const int wave = tid >> 6, lane = tid & 63;
  const int grp = lane >> 4, ln = lane & 15;
  const long e = (long)blk * 1024 + tid * 4;
  float w[10][4];
  if (isf) {
    const float* wp = (const float*)Wp;
#pragma unroll
    for (int n = 0; n < 10; n++) {
      float4 t = *(const float4*)&wp[(long)n * 524288 + e];
      w[n][0] = t.x; w[n][1] = t.y; w[n][2] = t.z; w[n][3] = t.w;
    }
  } else {
    const u16* wp = (const u16*)Wp;
#pragma unroll
    for (int n = 0; n < 10; n++) {
      uint2 u = *(const uint2*)&wp[(long)n * 524288 + e];
      w[n][0] = bf2f((u16)(u.x & 0xffff));
      w[n][1] = bf2f((u16)(u.x >> 16));
      w[n][2] = bf2f((u16)(u.y & 0xffff));
      w[n][3] = bf2f((u16)(u.y >> 16));
    }
  }
  __shared__ float sm[4][4][BB][16];  // [wave][grp][b][n] = 32 KB
  float4 xn = *(const float4*)&OUT[e];  // prefetch b=0
  for (int b = 0; b < BB; b++) {
    float4 x = xn;
    if (b < BB - 1) xn = *(const float4*)&OUT[(long)(b + 1) * 524288 + e];
    float acc[10];
#pragma unroll
    for (int n = 0; n < 10; n++)
      acc[n] = x.x * w[n][0] + x.y * w[n][1] + x.z * w[n][2] + x.w * w[n][3];
#pragma unroll
    for (int s = 1; s <= 8; s <<= 1)
#pragma unroll
      for (int n = 0; n < 10; n++) acc[n] += __shfl_xor(acc[n], s, 64);
    float v = 0.0f;
#pragma unroll
    for (int n = 0; n < 10; n++) v = (ln == n) ? acc[n] : v;
    if (ln < 10) sm[wave][grp][b][ln] = v;
  }
  __syncthreads();
  for (int o = tid; o < BB * 10; o += 256) {
    int b = o / 10, n = o - b * 10;
    float s = 0.0f;
#pragma unroll
    for (int w4 = 0; w4 < 4; w4++)
#pragma unroll
      for (int g = 0; g < 4; g++) s += sm[w4][g][b][n];
    PB2[(long)o * 512 + blk] = s;
  }
}

// proj stage 2 v2: reduce 512 partials per (b,n). grid (10,32), block 64
__global__ __launch_bounds__(64) void proj2_k(const float* __restrict__ PB2,
                                              const void* __restrict__ bp,
                                              void* __restrict__ out,
                                              const int* __restrict__ FLAG) {
  const int isf = *FLAG;
  int n = blockIdx.x, b = blockIdx.y;
  int o = b * 10 + n;
  int tid = threadIdx.x;
  float s = 0.0f;
  for (int j = tid; j < 512; j += 64) s += PB2[(long)o * 512 + j];
#pragma unroll
  for (int st = 32; st > 0; st >>= 1) s += __shfl_xor(s, st, 64);
  if (tid == 0) {
    s += ldi(bp, n, isf);
    if (isf) ((float*)out)[o] = s;
    else ((u16*)out)[o] = f2bf(s);
  }
}

// ---------------------------------------------------------------------------
extern "C" void kernel_launch(void* const* d_in, const int* in_sizes, int n_in,
                              void* d_out, int out_size, void* d_ws, size_t ws_size,
                              hipStream_t stream) {
  const void* xe = d_in[0];
  const void* mark = d_in[1];
  const void* cw = d_in[2];
  const void* Wq = d_in[3];
  const void* Wk = d_in[5];
  const void* Wv = d_in[7];
  const void* bv = d_in[8];
  const void* Wo = d_in[9];
  const void* bo = d_in[10];
  const void* Wff1 = d_in[11];
  const void* Wff2 = d_in[12];
  const void* lng = d_in[13];
  const void* lnb = d_in[14];
  const void* Wp = d_in[15];
  const void* bp = d_in[16];

  char* ws = (char*)d_ws;
  float* X      = (float*)(ws + 0L);               // 64 MiB f32 residual
  _Float16* XH  = (_Float16*)(ws + 67108864L);     // fp16 X-high, 32 MiB
  _Float16* XL  = (_Float16*)(ws + 100663296L);    // fp16 X-low*512 / AGh
  _Float16* AGh = (_Float16*)(ws + 100663296L);
  _Float16* ZH  = (_Float16*)(ws + 134217728L);    // Z-high chunk, 4 MiB
  _Float16* ZL  = (_Float16*)(ws + 138412032L);    // Z-low chunk, 4 MiB
  _Float16* Ph  = (_Float16*)(ws + 134217728L);    // Phase B: 8 MiB chunk
  float* CMp    = (float*)(ws + 134217728L);       // final: colmean partials
  float* wT     = (float*)(ws + 142606336L);       // conv wT (dead after embed)
  // Phase A overlays (all dead by Phase B):
  _Float16* KTH = (_Float16*)(ws + 142606336L);    // Wk^T split hi, 0.5 MiB
  _Float16* KTL = (_Float16*)(ws + 143130624L);    // Wk^T split lo
  _Float16* QTH = (_Float16*)(ws + 143654912L);    // Wq^T split hi
  _Float16* QTL = (_Float16*)(ws + 144179200L);    // Wq^T split lo
  _Float16* GH  = (_Float16*)(ws + 144703488L);    // G split hi, 0.5 MiB
  _Float16* GL  = (_Float16*)(ws + 145227776L);    // G split lo
  // Phase B overlays:
  _Float16* Wvh = (_Float16*)(ws + 142606336L);
  _Float16* Woh = (_Float16*)(ws + 143130624L);
  _Float16* W1h = (_Float16*)(ws + 143654912L);    // 2 MiB
  _Float16* W2h = (_Float16*)(ws + 145752064L);    // 2 MiB
  float* MV  = (float*)(ws + 147849216L);
  float* WGT = (float*)(ws + 147980288L);
  int*   DLY = (int*)(ws + 147981312L);
  int*  FLAG = (int*)(ws + 148068352L);
  float* S2  = (float*)(ws + 67108864L);           // FFN f32 (spans XH+XL)
  float* PB2 = (float*)(ws + 67108864L);           // proj partials (S2 dead)
  _Float16* Hb = (_Float16*)X;                     // FFN hidden (X dead)

  const long AD = (long)LL * DD;   // 524288
  const int M = BB * LL;           // 32768

  detect_k<<<1, 64, 0, stream>>>((const uint32_t*)mark, FLAG);
  wT_k<<<126, 256, 0, stream>>>(cw, wT, FLAG);
  conv_embed_k<<<dim3(64, 32), 256, 0, stream>>>(xe, wT, X, XH, XL, FLAG);

  for (int l = 0; l < 3; l++) {
    const long oW = (long)l * DD * DD;
    const long oB = (long)l * DD;
    const long oF = (long)l * DFF * DD;

    // ---- Phase A: delay selection via G-trick + fp16x2 split MFMA ----
    tsplit2_k<<<dim3(8, 8, 2), 256, 0, stream>>>(Wk, Wq, oW,
                                                 KTH, KTL, QTH, QTL, FLAG);
    gemm_z<<<dim3(4, 4), 256, 0, stream>>>(KTH, KTL, QTH, QTL,
                                           GH, GL, 512, 512, 512);
    hipMemsetAsync(MV, 0, (long)BB * LL * sizeof(float), stream);
    for (int cb = 0; cb < 8; cb++) {
      const long co = (long)cb * 4 * AD;
      gemm_z<<<dim3(4, 32), 256, 0, stream>>>(
          XH + co, XL + co, GH, GL, ZH, ZL, 4096, DD, DD);
      qkmv_hl<<<dim3(8, 8, 4), 256, 0, stream>>>(
          ZH, ZL, XH + co, XL + co, MV + (long)cb * 4 * LL);
    }
    topk_k<<<32, 256, 0, stream>>>(MV, WGT, DLY);

    // ---- Phase B: fp16 MFMA for V / agg / Wo / FFN ----
    wcvt6_k<<<1280, 256, 0, stream>>>(Wv, Wo, Wff1, Wff2, oW, oF,
                                      Wvh, Woh, W1h, W2h, FLAG);

    // V (fp16) per 8-batch chunk -> Ph (over ZH/ZL, dead), agg -> AGh
    for (int cb = 0; cb < 4; cb++) {
      const _Float16* xh = XH + (long)cb * 8 * AD;
      gemm_h<1 | 8><<<dim3(4, 64), 256, 0, stream>>>(
          xh, Wvh, bv, oB, nullptr, Ph, 8192, DD, DD, FLAG);
      agg_k<<<dim3(1024, 8), 128, 0, stream>>>(
          Ph, WGT + cb * 48, DLY + cb * 48, AGh + (long)cb * 8 * AD);
    }

    // X = X + AGh @ Wo^T + bo (full M, in-place residual)
    gemm_h<1 | 4><<<dim3(4, 256), 256, 0, stream>>>(
        AGh, Woh, bo, oB, X, X, M, DD, DD, FLAG);

    // x = decomp(X) -> S2 f32 (over XH/XL, both dead)
    decomp_k<<<dim3(2, 16, 32), 256, 0, stream>>>(X, S2);

    // FFN per 8-batch chunk: hidden -> Hb (X region, dead);
    // S2chunk = S2chunk + (gelu-hidden) @ W2^T.  FFN1 reads S2 f32 via gld16.
    for (int cb = 0; cb < 4; cb++) {
      float* xd = S2 + (long)cb * 8 * AD;
      gemm_hf<<<dim3(16, 64), 256, 0, stream>>>(
          xd, W1h, Hb, 8192, DFF, DD);
      gemm_h<4><<<dim3(4, 64), 256, 0, stream>>>(
          Hb, W2h, nullptr, 0, xd, xd, 8192, DD, DFF, FLAG);
    }

    // x = decomp(S2) -> X; then split X -> (XH, XL) for next layer
    decomp_k<<<dim3(2, 16, 32), 256, 0, stream>>>(S2, X);
    if (l < 2) split_k<<<8192, 256, 0, stream>>>(X, XH, XL, 16777216);
  }

  // final special layernorm + gelu + mask + projection
  ln_k<<<dim3(1024, 32), 256, 0, stream>>>(X, lng, lnb, S2, FLAG);
  colmean_k<<<dim3(2, 8, 32), 256, 0, stream>>>(S2, CMp);
  geluout_k<<<dim3(1024, 32), 256, 0, stream>>>(S2, CMp, mark, X, FLAG);
  proj1_k<<<512, 256, 0, stream>>>(X, Wp, PB2, FLAG);
  proj2_k<<<dim3(10, 32), 64, 0, stream>>>(PB2, bp, d_out, FLAG);
}